// Round 9
// baseline (354.771 us; speedup 1.0000x reference)
//
#include <hip/hip_runtime.h>

// N=50000, D=128 (both layers), K=256, EH=500000, ES=250000.
#define D_FEAT 128
#define K_DIM  256
#define EPB 4096

typedef __attribute__((ext_vector_type(8))) short bf16x8;
typedef __attribute__((ext_vector_type(4))) float f32x4;

__device__ __forceinline__ unsigned short f2b(float f) {
    union { float f; unsigned u; } cv; cv.f = f;
    return (unsigned short)((cv.u + 0x7fffu + ((cv.u >> 16) & 1u)) >> 16);
}

__device__ __forceinline__ unsigned pack2(float lo, float hi) {
    return (unsigned)f2b(lo) | ((unsigned)f2b(hi) << 16);
}

__device__ __forceinline__ uint4 pack8(float4 a, float4 b) {
    return make_uint4(pack2(a.x, a.y), pack2(a.z, a.w), pack2(b.x, b.y), pack2(b.z, b.w));
}

// unpack uint4 = 8 bf16 (low half of word = even element) and accumulate
__device__ __forceinline__ void addu4(float* a, uint4 v) {
    union { unsigned u; float f; } c;
    c.u = v.x << 16;         a[0] += c.f;
    c.u = v.x & 0xffff0000u; a[1] += c.f;
    c.u = v.y << 16;         a[2] += c.f;
    c.u = v.y & 0xffff0000u; a[3] += c.f;
    c.u = v.z << 16;         a[4] += c.f;
    c.u = v.z & 0xffff0000u; a[5] += c.f;
    c.u = v.w << 16;         a[6] += c.f;
    c.u = v.w & 0xffff0000u; a[7] += c.f;
}

// edge-array offset within the concatenated [H0|S0|H1|S1] space
__device__ __forceinline__ long yoff(int y, int EH, int ES) {
    return (long)((y + 1) >> 1) * EH + (long)(y >> 1) * ES;
}

// ---------------- bucket-level CSR build (both layers; y in 0..3) ----------------

__global__ __launch_bounds__(256)
void histB(const int* __restrict__ hd0, const int* __restrict__ sd0,
           const int* __restrict__ hd1, const int* __restrict__ sd1,
           int EH, int ES, int* __restrict__ bucketCnt, int nb2) {
    int y = blockIdx.y;
    const int* d = (y == 0) ? hd0 : (y == 1) ? sd0 : (y == 2) ? hd1 : sd1;
    int E = (y & 1) ? ES : EH;
    __shared__ int cnt[256];
    int t = threadIdx.x;
    cnt[t] = 0;
    __syncthreads();
    int i0 = blockIdx.x * EPB;
    #pragma unroll
    for (int j = 0; j < 16; ++j) {
        int i = i0 + j * 256 + t;
        if (i < E) atomicAdd(&cnt[d[i] >> 8], 1);
    }
    __syncthreads();
    if (t < nb2 && cnt[t] > 0) atomicAdd(&bucketCnt[y * nb2 + t], cnt[t]);
}

__global__ __launch_bounds__(64)
void scanBuckets(const int* __restrict__ bucketCnt, int* __restrict__ rpBucket,
                 int* __restrict__ bcur, int nb2) {
    int t = threadIdx.x;
    if (t < 4) {
        int run = 0;
        for (int i = 0; i < nb2; ++i) {
            rpBucket[t * (nb2 + 1) + i] = run;
            bcur[t * nb2 + i] = run;
            run += bucketCnt[t * nb2 + i];
        }
        rpBucket[t * (nb2 + 1) + nb2] = run;
    }
}

// Record: src (24 bits) | localDst (8 bits) << 24.
__global__ __launch_bounds__(256)
void binA(const int* __restrict__ hs0, const int* __restrict__ hd0,
          const int* __restrict__ ss0, const int* __restrict__ sd0,
          const int* __restrict__ hs1, const int* __restrict__ hd1,
          const int* __restrict__ ss1, const int* __restrict__ sd1,
          int EH, int ES, int* __restrict__ bcur, unsigned* __restrict__ recs,
          int nb2) {
    int y = blockIdx.y;
    const int* src = (y == 0) ? hs0 : (y == 1) ? ss0 : (y == 2) ? hs1 : ss1;
    const int* dst = (y == 0) ? hd0 : (y == 1) ? sd0 : (y == 2) ? hd1 : sd1;
    int E = (y & 1) ? ES : EH;
    unsigned* rb = recs + yoff(y, EH, ES);

    __shared__ int cnt[256];
    int t = threadIdx.x;
    cnt[t] = 0;
    __syncthreads();
    int i0 = blockIdx.x * EPB;
    #pragma unroll
    for (int j = 0; j < 16; ++j) {
        int i = i0 + j * 256 + t;
        if (i < E) atomicAdd(&cnt[dst[i] >> 8], 1);
    }
    __syncthreads();
    int c = cnt[t];
    __syncthreads();
    if (t < nb2 && c > 0) cnt[t] = atomicAdd(&bcur[y * nb2 + t], c);
    __syncthreads();
    #pragma unroll
    for (int j = 0; j < 16; ++j) {
        int i = i0 + j * 256 + t;
        if (i < E) {
            int dd = dst[i];
            int slot = atomicAdd(&cnt[dd >> 8], 1);
            rb[slot] = (unsigned)src[i] | ((unsigned)(dd & 255) << 24);
        }
    }
}

__global__ __launch_bounds__(256)
void placeB(const unsigned* __restrict__ recs, const int* __restrict__ rpBucket,
            int* __restrict__ rpAll, int* __restrict__ srcAll,
            int EH, int ES, int n, int nb2) {
    int y = blockIdx.y;
    int b = blockIdx.x;
    int E = (y & 1) ? ES : EH;
    int* rp = rpAll + (size_t)y * (n + 1);
    long off = yoff(y, EH, ES);
    const unsigned* rb = recs + off;
    int* sb = srcAll + off;
    int e0 = rpBucket[y * (nb2 + 1) + b];
    int e1 = rpBucket[y * (nb2 + 1) + b + 1];
    int nodeBase = b << 8;

    __shared__ int cnt[256];
    __shared__ int sh[256];
    int t = threadIdx.x;
    cnt[t] = 0;
    __syncthreads();
    for (int e = e0 + t; e < e1; e += 256)
        atomicAdd(&cnt[rb[e] >> 24], 1);
    __syncthreads();
    sh[t] = cnt[t];
    __syncthreads();
    for (int o = 1; o < 256; o <<= 1) {
        int x = (t >= o) ? sh[t - o] : 0;
        __syncthreads();
        sh[t] += x;
        __syncthreads();
    }
    int base = e0 + (t ? sh[t - 1] : 0);
    if (nodeBase + t < n) rp[nodeBase + t] = base;
    if (b == 0 && t == 0) rp[n] = E;
    cnt[t] = base;
    __syncthreads();
    for (int e = e0 + t; e < e1; e += 256) {
        unsigned r = rb[e];
        int p = atomicAdd(&cnt[r >> 24], 1);
        sb[p] = (int)(r & 0x00FFFFFFu);
    }
}

// ---------------- upfront bf16 prep ----------------
__global__ __launch_bounds__(256)
void prep_static(const float4* __restrict__ x, const float4* __restrict__ hbar0,
                 const float4* __restrict__ hbar1,
                 uint4* __restrict__ hb0, uint4* __restrict__ db0,
                 uint4* __restrict__ hb1, uint4* __restrict__ z, int n16) {
    int i = blockIdx.x * 256 + threadIdx.x;
    if (i >= n16) return;
    float4 xa = x[i * 2],     xb = x[i * 2 + 1];
    float4 ba = hbar0[i * 2], bb = hbar0[i * 2 + 1];
    float4 ca = hbar1[i * 2], cb = hbar1[i * 2 + 1];
    hb0[i] = pack8(ba, bb);
    db0[i] = pack8(make_float4(xa.x - ba.x, xa.y - ba.y, xa.z - ba.z, xa.w - ba.w),
                   make_float4(xb.x - bb.x, xb.y - bb.y, xb.z - bb.z, xb.w - bb.w));
    hb1[i] = pack8(ca, cb);
    int g = i >> 4, seg = i & 15;
    z[(size_t)g * 32 + seg] = pack8(xa, xb);   // z left half = bf16(x row)
}

__global__ __launch_bounds__(256)
void conv_weights(const float* __restrict__ W0, unsigned short* __restrict__ Wb0,
                  const float* __restrict__ W1, unsigned short* __restrict__ Wb1) {
    int i = blockIdx.x * 256 + threadIdx.x;
    if (i < 128 * 256) Wb0[i] = f2b(W0[i]);
    if (i < 64 * 256) {
        int r = i >> 8;
        Wb1[i] = (r < 47) ? f2b(W1[i]) : (unsigned short)0;
    }
}

// ---------------- aggregation: one full wave per node ----------------
__global__ __launch_bounds__(256)
void aggregate_z(const uint4* __restrict__ HB, const uint4* __restrict__ DB,
                 const int* __restrict__ rpH, const int* __restrict__ srcH,
                 const int* __restrict__ rpS, const int* __restrict__ srcS,
                 uint4* __restrict__ z, int n) {
    int g = blockIdx.x * 4 + (threadIdx.x >> 6);
    if (g >= n) return;
    int lane = threadIdx.x & 63;
    int j = lane >> 4, l = lane & 15;

    int hb_ = rpH[g], he = rpH[g + 1];
    int sb  = rpS[g], se = rpS[g + 1];

    float a[8] = {0, 0, 0, 0, 0, 0, 0, 0};
    for (int e0 = hb_; e0 < he; e0 += 8) {
        int e1 = e0 + j, e2 = e0 + 4 + j;
        uint4 v1 = make_uint4(0, 0, 0, 0), v2 = make_uint4(0, 0, 0, 0);
        if (e1 < he) v1 = HB[(size_t)srcH[e1] * 16 + l];
        if (e2 < he) v2 = HB[(size_t)srcH[e2] * 16 + l];
        addu4(a, v1); addu4(a, v2);
    }
    float d[8] = {0, 0, 0, 0, 0, 0, 0, 0};
    for (int e0 = sb; e0 < se; e0 += 8) {
        int e1 = e0 + j, e2 = e0 + 4 + j;
        uint4 v1 = make_uint4(0, 0, 0, 0), v2 = make_uint4(0, 0, 0, 0);
        if (e1 < se) v1 = DB[(size_t)srcS[e1] * 16 + l];
        if (e2 < se) v2 = DB[(size_t)srcS[e2] * 16 + l];
        addu4(d, v1); addu4(d, v2);
    }

    float rH = 1.0f / fmaxf((float)(he - hb_), 1.0f);
    float rS = 1.0f / fmaxf((float)(se - sb), 1.0f);
    float s[8];
    #pragma unroll
    for (int i = 0; i < 8; ++i) {
        float v = a[i] * rH + d[i] * rS;
        v += __shfl_xor(v, 16);
        v += __shfl_xor(v, 32);
        s[i] = v;
    }
    if (j == 0) {
        uint4 rv = make_uint4(pack2(s[0], s[1]), pack2(s[2], s[3]),
                              pack2(s[4], s[5]), pack2(s[6], s[7]));
        z[(size_t)g * 32 + 16 + l] = rv;   // right half: h_neigh
    }
}

// ---------------- MFMA GEMM layer 0 (swapped operands) ----------------
// aF = W-row frag, bF = Z-row frag => D[row=(quad*4+r)] = output col c,
// D[col=(lane&15)] = output row m. Lane holds 4 CONSECUTIVE c per tile.
// Epilogue: h1 = relu(.+b0); writes z-left = bf16(h1), db1 = bf16(h1-hbar1).
__global__ __launch_bounds__(256)
void gemm_mfma_l0(const unsigned short* __restrict__ Z, const unsigned short* __restrict__ Wb,
                  const float* __restrict__ bias, const float* __restrict__ hbar1,
                  unsigned short* __restrict__ db1, unsigned short* __restrict__ zl, int n) {
    int wave = threadIdx.x >> 6;
    int lane = threadIdx.x & 63;
    int quad = lane >> 4;
    int lid  = lane & 15;
    int m0 = blockIdx.x * 64 + wave * 16;
    int m  = m0 + lid;
    int mc = (m < n) ? m : (n - 1);      // clamp loads; stores guarded
    const short* Zs = (const short*)Z;
    const short* Ws = (const short*)Wb;

    // all 8 Z-frags upfront (MLP: 8 loads in flight)
    bf16x8 zf[8];
    #pragma unroll
    for (int k0 = 0; k0 < 8; ++k0)
        zf[k0] = *(const bf16x8*)(Zs + (size_t)mc * 256 + k0 * 32 + quad * 8);

    f32x4 acc[8] = {};
    #pragma unroll
    for (int t = 0; t < 8; ++t) {
        #pragma unroll
        for (int k0 = 0; k0 < 8; ++k0) {
            bf16x8 wf = *(const bf16x8*)(Ws + (size_t)(t * 16 + lid) * 256 + k0 * 32 + quad * 8);
            acc[t] = __builtin_amdgcn_mfma_f32_16x16x32_bf16(wf, zf[k0], acc[t], 0, 0, 0);
        }
    }

    if (m >= n) return;
    #pragma unroll
    for (int t = 0; t < 8; ++t) {
        int c0 = t * 16 + quad * 4;
        float4 bv = *(const float4*)&bias[c0];
        float4 hb = *(const float4*)&hbar1[(size_t)m * 128 + c0];
        float h0 = fmaxf(acc[t][0] + bv.x, 0.f);
        float h1v = fmaxf(acc[t][1] + bv.y, 0.f);
        float h2 = fmaxf(acc[t][2] + bv.z, 0.f);
        float h3 = fmaxf(acc[t][3] + bv.w, 0.f);
        *(ushort4*)&db1[(size_t)m * 128 + c0] =
            make_ushort4(f2b(h0 - hb.x), f2b(h1v - hb.y), f2b(h2 - hb.z), f2b(h3 - hb.w));
        *(ushort4*)&zl[(size_t)m * 256 + c0] =
            make_ushort4(f2b(h0), f2b(h1v), f2b(h2), f2b(h3));
    }
}

// ---------------- MFMA GEMM layer 1 (swapped operands) -> f32 out ----------------
template<int NT>
__global__ __launch_bounds__(256)
void gemm_mfma(const unsigned short* __restrict__ Z, const unsigned short* __restrict__ Wb,
               const float* __restrict__ bias, float* __restrict__ out, int n, int COLS) {
    int wave = threadIdx.x >> 6;
    int lane = threadIdx.x & 63;
    int quad = lane >> 4;
    int lid  = lane & 15;
    int m0 = blockIdx.x * 64 + wave * 16;
    int m  = m0 + lid;
    int mc = (m < n) ? m : (n - 1);
    const short* Zs = (const short*)Z;
    const short* Ws = (const short*)Wb;

    bf16x8 zf[8];
    #pragma unroll
    for (int k0 = 0; k0 < 8; ++k0)
        zf[k0] = *(const bf16x8*)(Zs + (size_t)mc * 256 + k0 * 32 + quad * 8);

    f32x4 acc[NT] = {};
    #pragma unroll
    for (int t = 0; t < NT; ++t) {
        #pragma unroll
        for (int k0 = 0; k0 < 8; ++k0) {
            bf16x8 wf = *(const bf16x8*)(Ws + (size_t)(t * 16 + lid) * 256 + k0 * 32 + quad * 8);
            acc[t] = __builtin_amdgcn_mfma_f32_16x16x32_bf16(wf, zf[k0], acc[t], 0, 0, 0);
        }
    }

    if (m >= n) return;
    #pragma unroll
    for (int t = 0; t < NT; ++t) {
        #pragma unroll
        for (int r = 0; r < 4; ++r) {
            int c = t * 16 + quad * 4 + r;
            if (c < COLS)
                out[(size_t)m * COLS + c] = fmaxf(acc[t][r] + bias[c], 0.f);
        }
    }
}

extern "C" void kernel_launch(void* const* d_in, const int* in_sizes, int n_in,
                              void* d_out, int out_size, void* d_ws, size_t ws_size,
                              hipStream_t stream) {
    const float* x     = (const float*)d_in[0];
    const float* hbar0 = (const float*)d_in[1];
    const float* hbar1 = (const float*)d_in[2];
    const float* W0    = (const float*)d_in[3];
    const float* b0    = (const float*)d_in[4];
    const float* W1    = (const float*)d_in[5];
    const float* b1    = (const float*)d_in[6];
    const int* hs0 = (const int*)d_in[7];
    const int* hd0 = (const int*)d_in[8];
    const int* ss0 = (const int*)d_in[9];
    const int* sd0 = (const int*)d_in[10];
    const int* hs1 = (const int*)d_in[11];
    const int* hd1 = (const int*)d_in[12];
    const int* ss1 = (const int*)d_in[13];
    const int* sd1 = (const int*)d_in[14];

    const int n   = in_sizes[0] / D_FEAT;   // 50000
    const int EH  = in_sizes[7];            // 500000
    const int ES  = in_sizes[9];            // 250000
    const int nb2 = (n + 255) / 256;        // 196 dst buckets per etype

    // ---- workspace layout ----
    int* bucketCnt = (int*)d_ws;                       // 4*nb2
    int* rpBucket  = bucketCnt + 4 * nb2;              // 4*(nb2+1)
    int* bcur      = rpBucket + 4 * (nb2 + 1);         // 4*nb2
    int* rpAll     = bcur + 4 * nb2;                   // 4*(n+1)
    int* srcAll    = rpAll + 4 * (size_t)(n + 1);      // 2EH+2ES
    unsigned* recs = (unsigned*)(srcAll + 2 * (size_t)EH + 2 * (size_t)ES); // 2EH+2ES
    size_t int_words = (size_t)12 * nb2 + 4 + 4 * (size_t)(n + 1)
                     + 4 * (size_t)EH + 4 * (size_t)ES;
    int_words = (int_words + 3) & ~(size_t)3;                          // 16 B align
    unsigned short* hb0 = (unsigned short*)((int*)d_ws + int_words);   // n*128 bf16
    unsigned short* db0 = hb0 + (size_t)n * D_FEAT;                    // n*128 bf16
    unsigned short* hb1 = db0 + (size_t)n * D_FEAT;                    // n*128 bf16
    unsigned short* db1 = hb1 + (size_t)n * D_FEAT;                    // n*128 bf16
    unsigned short* z   = db1 + (size_t)n * D_FEAT;                    // n*256 bf16
    unsigned short* Wb0 = z + (size_t)n * K_DIM;                       // 128*256
    unsigned short* Wb1 = Wb0 + 128 * 256;                             // 64*256

    const int* rpH0 = rpAll;
    const int* rpS0 = rpAll + (size_t)(n + 1);
    const int* rpH1 = rpAll + 2 * (size_t)(n + 1);
    const int* rpS1 = rpAll + 3 * (size_t)(n + 1);
    int* srcH0 = srcAll;
    int* srcS0 = srcAll + (size_t)EH;
    int* srcH1 = srcAll + (size_t)EH + ES;
    int* srcS1 = srcAll + 2 * (size_t)EH + ES;

    dim3 blk(256);
    int binb  = (EH + EPB - 1) / EPB;
    int prepb = ((n * 16) + 255) / 256;
    int aggb  = (n + 3) / 4;
    int gemmb = (n + 63) / 64;

    // ---- CSR build for BOTH layers + static prep ----
    hipMemsetAsync(bucketCnt, 0, 4 * (size_t)nb2 * sizeof(int), stream);
    conv_weights<<<128, blk, 0, stream>>>(W0, Wb0, W1, Wb1);
    histB<<<dim3(binb, 4), blk, 0, stream>>>(hd0, sd0, hd1, sd1, EH, ES, bucketCnt, nb2);
    scanBuckets<<<1, 64, 0, stream>>>(bucketCnt, rpBucket, bcur, nb2);
    binA<<<dim3(binb, 4), blk, 0, stream>>>(hs0, hd0, ss0, sd0, hs1, hd1, ss1, sd1,
                                            EH, ES, bcur, recs, nb2);
    placeB<<<dim3(nb2, 4), blk, 0, stream>>>(recs, rpBucket, rpAll, srcAll, EH, ES, n, nb2);
    prep_static<<<prepb, blk, 0, stream>>>((const float4*)x, (const float4*)hbar0,
                                           (const float4*)hbar1, (uint4*)hb0, (uint4*)db0,
                                           (uint4*)hb1, (uint4*)z, n * 16);

    // ---------------- Layer 0 ----------------
    aggregate_z<<<aggb, blk, 0, stream>>>((const uint4*)hb0, (const uint4*)db0,
                                          rpH0, srcH0, rpS0, srcS0, (uint4*)z, n);
    gemm_mfma_l0<<<gemmb, blk, 0, stream>>>(z, Wb0, b0, hbar1, db1, z, n);

    // ---------------- Layer 1 ----------------
    aggregate_z<<<aggb, blk, 0, stream>>>((const uint4*)hb1, (const uint4*)db1,
                                          rpH1, srcH1, rpS1, srcS1, (uint4*)z, n);
    gemm_mfma<3><<<gemmb, blk, 0, stream>>>(z, Wb1, b1, (float*)d_out, n, 47);
}